// Round 5
// baseline (1483.459 us; speedup 1.0000x reference)
//
#include <hip/hip_runtime.h>
#include <hip/hip_bf16.h>
#include <stdint.h>
#include <stddef.h>

using bf16 = __hip_bfloat16;
typedef __attribute__((ext_vector_type(8))) short short8;   // 8 bf16 (4 VGPRs)
typedef __attribute__((ext_vector_type(4))) float f32x4;
typedef __attribute__((ext_vector_type(2))) float f32x2;

#define T_TOK 2048
#define HD    2048
#define NH    32
#define NKV   16
#define DKh   128
#define DVh   128

// ---------- helpers ----------
__device__ __forceinline__ void bf2f(uint32_t u, float& a, float& b) {
    union { uint32_t i; float f; } x;
    x.i = u << 16;          a = x.f;
    x.i = u & 0xffff0000u;  b = x.f;
}

__device__ __forceinline__ void gload16(const void* g, void* l) {
    __builtin_amdgcn_global_load_lds(
        (const __attribute__((address_space(1))) void*)g,
        (__attribute__((address_space(3))) void*)l, 16, 0, 0);
}

__device__ __forceinline__ void store_c(bf16* C, size_t off, float v) { C[off] = __float2bfloat16(v); }
__device__ __forceinline__ void store_c(float* C, size_t off, float v) { C[off] = v; }

__device__ __forceinline__ f32x2 lo2(float4 v) { f32x2 r; r.x = v.x; r.y = v.y; return r; }
__device__ __forceinline__ f32x2 hi2(float4 v) { f32x2 r; r.x = v.z; r.y = v.w; return r; }

// DPP butterfly add within rows of 16 lanes (VALU latency, no LDS)
template <int CTRL>
__device__ __forceinline__ float dppadd(float x) {
    int y = __builtin_amdgcn_update_dpp(0, __float_as_int(x), CTRL, 0xf, 0xf, true);
    return x + __int_as_float(y);
}
__device__ __forceinline__ float red16(float x) {
    x = dppadd<0xB1>(x);    // quad_perm [1,0,3,2]  : xor 1
    x = dppadd<0x4E>(x);    // quad_perm [2,3,0,1]  : xor 2
    x = dppadd<0x141>(x);   // row_half_mirror      : xor 4
    x = dppadd<0x140>(x);   // row_mirror           : xor 8
    return x;
}

// ---------- convert fp32 -> bf16 elementwise ----------
__global__ __launch_bounds__(256) void f2b_kernel(
    const float* __restrict__ in, bf16* __restrict__ out, int n)
{
    int i = blockIdx.x * 256 + threadIdx.x;
    if (i < n) out[i] = __float2bfloat16(in[i]);
}

// ---------- transpose+convert: in fp32 [R][C] -> out bf16 [C][R] ----------
__global__ __launch_bounds__(256) void transpose_kernel(
    const float* __restrict__ in, bf16* __restrict__ out, int R, int C)
{
    __shared__ bf16 tile[32][33];
    int c0 = blockIdx.x * 32, r0 = blockIdx.y * 32;
    int x = threadIdx.x;
    int y = threadIdx.y;
    #pragma unroll
    for (int i = y; i < 32; i += 8)
        tile[i][x] = __float2bfloat16(in[(size_t)(r0 + i) * C + c0 + x]);
    __syncthreads();
    #pragma unroll
    for (int i = y; i < 32; i += 8)
        out[(size_t)(c0 + i) * R + r0 + x] = tile[x][i];
}

// ---------- transpose bf16: in [R][C] -> out [C][R] ----------
__global__ __launch_bounds__(256) void transpose_bf_kernel(
    const bf16* __restrict__ in, bf16* __restrict__ out, int R, int C)
{
    __shared__ bf16 tile[32][33];
    int c0 = blockIdx.x * 32, r0 = blockIdx.y * 32;
    int x = threadIdx.x;
    int y = threadIdx.y;
    #pragma unroll
    for (int i = y; i < 32; i += 8)
        tile[i][x] = in[(size_t)(r0 + i) * C + c0 + x];
    __syncthreads();
    #pragma unroll
    for (int i = y; i < 32; i += 8)
        out[(size_t)(c0 + i) * R + r0 + x] = tile[x][i];
}

// ---------- build [Wa|Wb|0] transposed: out bf16 [128][2048] ----------
__global__ __launch_bounds__(256) void build_wab_kernel(
    const float* __restrict__ Wa, const float* __restrict__ Wb, bf16* __restrict__ out)
{
    int k = blockIdx.x * 256 + threadIdx.x;
    int n = blockIdx.y;
    float v = 0.f;
    if (n < 32)      v = Wa[(size_t)k * 32 + n];
    else if (n < 64) v = Wb[(size_t)k * 32 + (n - 32)];
    out[(size_t)n * 2048 + k] = __float2bfloat16(v);
}

// ---------- MFMA GEMM: C[M,N] = A[M,K] * B^T (B given as [N,K]), bf16 in ----------
template <typename OutT>
__global__ __launch_bounds__(256) void gemm_bt_kernel(
    const bf16* __restrict__ A, const bf16* __restrict__ B, OutT* __restrict__ C,
    int M, int N, int K)
{
    __shared__ short sA[128 * 64];
    __shared__ short sB[128 * 64];
    const int tid  = threadIdx.x;
    const int w    = tid >> 6;
    const int lane = tid & 63;
    const int quad = lane >> 4;
    const int r    = lane & 15;
    const int wm   = w >> 1, wn = w & 1;
    const int bm   = blockIdx.x, bn = blockIdx.y;
    const int lrow = lane >> 3;
    const int lp   = lane & 7;
    const int lc   = lp ^ lrow;

    f32x4 acc[4][4] = {};

    const int nkb = K >> 6;
    for (int kb = 0; kb < nkb; ++kb) {
        __syncthreads();
        #pragma unroll
        for (int it = 0; it < 4; ++it) {
            int grp = w * 4 + it;
            int rr  = grp * 8 + lrow;
            const bf16* ga = A + (size_t)(bm * 128 + rr) * K + kb * 64 + lc * 8;
            gload16(ga, (void*)(sA + grp * 512));
            const bf16* gb = B + (size_t)(bn * 128 + rr) * K + kb * 64 + lc * 8;
            gload16(gb, (void*)(sB + grp * 512));
        }
        __syncthreads();

        #pragma unroll
        for (int kk = 0; kk < 2; ++kk) {
            short8 av[4], bv[4];
            #pragma unroll
            for (int i = 0; i < 4; ++i) {
                int p   = (kk * 4 + quad) ^ (r & 7);
                int row = wm * 64 + i * 16 + r;
                av[i] = *(const short8*)(sA + row * 64 + p * 8);
                int rowb = wn * 64 + i * 16 + r;
                bv[i] = *(const short8*)(sB + rowb * 64 + p * 8);
            }
            #pragma unroll
            for (int i = 0; i < 4; ++i)
                #pragma unroll
                for (int j = 0; j < 4; ++j)
                    acc[i][j] = __builtin_amdgcn_mfma_f32_16x16x32_bf16(
                        av[i], bv[j], acc[i][j], 0, 0, 0);
        }
    }

    #pragma unroll
    for (int i = 0; i < 4; ++i) {
        int row0 = bm * 128 + wm * 64 + i * 16 + quad * 4;
        #pragma unroll
        for (int j = 0; j < 4; ++j) {
            int col = bn * 128 + wn * 64 + j * 16 + r;
            #pragma unroll
            for (int e = 0; e < 4; ++e)
                store_c(C, (size_t)(row0 + e) * N + col, acc[i][j][e]);
        }
    }
}

// ---------- conv+silu+l2norm for q,k (fp32, T-major chunk layout) ----------
// output layout: [hkv*16 + (d>>3)][T][8]  (so recur loads are base + t*32B)
__global__ __launch_bounds__(128) void conv_qk_kernel(
    const bf16* __restrict__ mixed, const float* __restrict__ cq,
    const float* __restrict__ ck, float* __restrict__ qn, float* __restrict__ kn)
{
    int t = blockIdx.x;
    int g = blockIdx.y;
    int d = threadIdx.x;
    int isq = (g < NKV) ? 1 : 0;
    int h   = isq ? g : g - NKV;
    int cl  = h * DKh + d;
    int c   = (isq ? 0 : 2048) + cl;
    const float* cw = isq ? cq : ck;
    float acc = 0.f;
    #pragma unroll
    for (int j = 0; j < 4; ++j) {
        int ts = t - 3 + j;
        if (ts >= 0)
            acc += __bfloat162float(mixed[(size_t)ts * 8192 + c]) * cw[cl * 4 + j];
    }
    float s = acc / (1.f + __expf(-acc));  // silu
    float ss = s * s;
    #pragma unroll
    for (int m = 1; m < 64; m <<= 1) ss += __shfl_xor(ss, m, 64);
    __shared__ float part[2];
    if ((threadIdx.x & 63) == 0) part[threadIdx.x >> 6] = ss;
    __syncthreads();
    float sum = part[0] + part[1];
    float rn = rsqrtf(sum + 1e-6f);
    float outv = s * rn;
    if (isq) outv *= 0.08838834764831845f;   // DK^-0.5 folded into q
    int chunk = h * 16 + (d >> 3);
    (isq ? qn : kn)[((size_t)chunk * T_TOK + t) * 8 + (d & 7)] = outv;
}

// ---------- conv+silu for v ----------
__global__ __launch_bounds__(256) void conv_v_kernel(
    const bf16* __restrict__ mixed, const float* __restrict__ cv, bf16* __restrict__ vv)
{
    int idx = blockIdx.x * 256 + threadIdx.x;
    int t = idx >> 12, c = idx & 4095;
    float acc = 0.f;
    #pragma unroll
    for (int j = 0; j < 4; ++j) {
        int ts = t - 3 + j;
        if (ts >= 0)
            acc += __bfloat162float(mixed[(size_t)ts * 8192 + 4096 + c]) * cv[c * 4 + j];
    }
    vv[idx] = __float2bfloat16(acc / (1.f + __expf(-acc)));
}

// ---------- gating -> ebz[h][t] = {exp(g), beta} ----------
__global__ __launch_bounds__(256) void gating_kernel(
    const float* __restrict__ ab, const float* __restrict__ dt_bias,
    const float* __restrict__ A_log, f32x2* __restrict__ ebz)
{
    int i = blockIdx.x * 256 + threadIdx.x;   // h*2048 + t
    int h = i >> 11, t = i & 2047;
    float a  = ab[(size_t)t * 128 + h] + dt_bias[h];
    float sp = (a <= 20.f) ? log1pf(__expf(a)) : a;
    float gg = -__expf(A_log[h]) * sp;
    float b  = ab[(size_t)t * 128 + 32 + h];
    f32x2 r; r.x = __expf(gg); r.y = 1.f / (1.f + __expf(-b));
    ebz[i] = r;
}

// ---------- gated delta-rule recurrence ----------
// T-major layouts: krt/qrt [16kv][16dkg][T][8]f32, vrt [h*128+dv][T]bf16,
// ebz [h][T]{eg,beta}. grid (32 h, 8 sp), block 256: thread (dvl=tid>>4,
// dkg=tid&15) owns S[dkg*8..+8][dv] as 4 packed f32x2; DPP red16 reductions;
// depth-8 register prefetch with imm-offset loads from one pointer per array.
#define PF 8

__global__ __launch_bounds__(256) void recur_kernel(
    const float* __restrict__ qrt, const float* __restrict__ krt,
    const bf16* __restrict__ vrt, const f32x2* __restrict__ ebz,
    bf16* __restrict__ o)
{
    int h   = blockIdx.x;
    int sp  = blockIdx.y;
    int tid = threadIdx.x;
    int dvl = tid >> 4;
    int dkg = tid & 15;
    int dv  = sp * 16 + dvl;
    int hkv = h >> 1;                       // GQA repeat-interleave
    bool writer = (dkg == 0);

    const float4* kp = (const float4*)(krt + ((size_t)(hkv * 16 + dkg) * T_TOK) * 8);
    const float4* qp = (const float4*)(qrt + ((size_t)(hkv * 16 + dkg) * T_TOK) * 8);
    const bf16*   vp = vrt + ((size_t)h * DVh + dv) * T_TOK;
    const f32x2*  ep = ebz + (size_t)h * T_TOK;
    bf16* optr = o + h * DVh + dv;

    f32x2 S0 = {0.f, 0.f}, S1 = {0.f, 0.f}, S2 = {0.f, 0.f}, S3 = {0.f, 0.f};

    // prefetch slots (rows t .. t+7); refills read up to 7 rows OOB at the
    // very end — covered by adjacent ws regions / pad, values unused.
    float4 k0[PF], k1[PF], q0[PF], q1[PF];
    bf16   vs[PF];
    f32x2  es[PF];
    #pragma unroll
    for (int s = 0; s < PF; ++s) {
        k0[s] = kp[2 * s]; k1[s] = kp[2 * s + 1];
        q0[s] = qp[2 * s]; q1[s] = qp[2 * s + 1];
        vs[s] = vp[s];
        es[s] = ep[s];
    }

    #pragma unroll 1
    for (int t = 0; t < T_TOK; t += PF) {
        #pragma unroll
        for (int s = 0; s < PF; ++s) {
            float4 ka = k0[s], kb = k1[s], qa = q0[s], qb = q1[s];
            float vc = __bfloat162float(vs[s]);
            float egt = es[s].x, bt = es[s].y;
            // refill slot s with row t+s+PF (imm offsets, same base pointers)
            k0[s] = kp[2 * (PF + s)]; k1[s] = kp[2 * (PF + s) + 1];
            q0[s] = qp[2 * (PF + s)]; q1[s] = qp[2 * (PF + s) + 1];
            vs[s] = vp[PF + s];
            es[s] = ep[PF + s];
            // step (packed fp32)
            f32x2 e2; e2.x = egt; e2.y = egt;
            S0 *= e2; S1 *= e2; S2 *= e2; S3 *= e2;
            f32x2 pa = S0 * lo2(ka);
            f32x2 pb = S1 * hi2(ka);
            pa += S2 * lo2(kb);
            pb += S3 * hi2(kb);
            f32x2 ps = pa + pb;
            float kv = red16(ps.x + ps.y);
            float dvv = bt * (vc - kv);
            f32x2 d2; d2.x = dvv; d2.y = dvv;
            S0 += lo2(ka) * d2; S1 += hi2(ka) * d2;
            S2 += lo2(kb) * d2; S3 += hi2(kb) * d2;
            f32x2 oa = S0 * lo2(qa);
            f32x2 ob = S1 * hi2(qa);
            oa += S2 * lo2(qb);
            ob += S3 * hi2(qb);
            f32x2 os = oa + ob;
            float op = red16(os.x + os.y);
            if (writer) optr[(size_t)(t + s) * 4096] = __float2bfloat16(op);
        }
        kp += 2 * PF; qp += 2 * PF; vp += PF; ep += PF;
    }
}

// ---------- gated RMSNorm ----------
__global__ __launch_bounds__(256) void normgate_kernel(
    const bf16* __restrict__ o, const bf16* __restrict__ gate,
    const float* __restrict__ w, bf16* __restrict__ og)
{
    int grp  = blockIdx.x * 4 + (threadIdx.x >> 6);
    int lane = threadIdx.x & 63;
    int t = grp >> 5, h = grp & 31;
    size_t base = (size_t)t * 4096 + h * DVh;
    uint32_t uo = *(const uint32_t*)(o + base + lane * 2);
    float a, b; bf2f(uo, a, b);
    float ss = a * a + b * b;
    #pragma unroll
    for (int m = 1; m < 64; m <<= 1) ss += __shfl_xor(ss, m, 64);
    float rn = rsqrtf(ss * (1.f / 128.f) + 1e-5f);
    uint32_t ug = *(const uint32_t*)(gate + base + lane * 2);
    float ga, gb; bf2f(ug, ga, gb);
    float wa = w[lane * 2], wb = w[lane * 2 + 1];
    float oa = a * rn * wa * (ga / (1.f + __expf(-ga)));
    float ob = b * rn * wb * (gb / (1.f + __expf(-gb)));
    og[base + lane * 2]     = __float2bfloat16(oa);
    og[base + lane * 2 + 1] = __float2bfloat16(ob);
}

// ---------- launch ----------
extern "C" void kernel_launch(void* const* d_in, const int* in_sizes, int n_in,
                              void* d_out, int out_size, void* d_ws, size_t ws_size,
                              hipStream_t stream)
{
    const float* h       = (const float*)d_in[0];
    const float* Wq      = (const float*)d_in[1];
    const float* Wk      = (const float*)d_in[2];
    const float* Wv      = (const float*)d_in[3];
    const float* Wa      = (const float*)d_in[4];
    const float* Wb      = (const float*)d_in[5];
    const float* Wg      = (const float*)d_in[6];
    const float* conv_q  = (const float*)d_in[7];
    const float* conv_k  = (const float*)d_in[8];
    const float* conv_v  = (const float*)d_in[9];
    const float* dt_bias = (const float*)d_in[10];
    const float* A_log   = (const float*)d_in[11];
    const float* onw     = (const float*)d_in[12];
    const float* Wo      = (const float*)d_in[13];
    float* out = (float*)d_out;

    char* ws = (char*)d_ws;
    bf16*  WqkvT = (bf16*)ws;   ws += (size_t)8192 * 2048 * 2;   // 33.5 MB
    bf16*  WgT   = (bf16*)ws;   ws += (size_t)4096 * 2048 * 2;   // 16.8 MB (reused as qrt)
    bf16*  WoT   = (bf16*)ws;   ws += (size_t)2048 * 4096 * 2;   // 16.8 MB
    bf16*  WabT  = (bf16*)ws;   ws += (size_t)128 * 2048 * 2;
    bf16*  hb    = (bf16*)ws;   ws += (size_t)2048 * 2048 * 2;
    bf16*  mixed = (bf16*)ws;   ws += (size_t)2048 * 8192 * 2;   // 33.5 MB
    float* ab    = (float*)ws;  ws += (size_t)2048 * 128 * 4;
    float* krt   = (float*)ws;  ws += (size_t)2048 * 2048 * 4;   // 16.8 MB fp32
    bf16*  vvb   = (bf16*)ws;   ws += (size_t)2048 * 4096 * 2;   // 16.8 MB [t][c]
    f32x2* ebz   = (f32x2*)ws;  ws += (size_t)32 * 2048 * 8;     // 512 KB
    bf16*  vrt   = (bf16*)ws;   ws += (size_t)4096 * 2048 * 2;   // 16.8 MB [c][t]
    ws += 32768;                                                 // OOB-prefetch pad
    // aliases over dead regions (stream-ordered lifetimes):
    float* qrt  = (float*)WgT;                     // WgT dead after gate GEMM
    bf16*  ob   = WqkvT;                           // WqkvT dead after qkv GEMM
    bf16*  gate = WqkvT + (size_t)2048 * 4096;     // second half of WqkvT region
    bf16*  og   = mixed;                           // mixed dead after conv kernels

    dim3 tb(32, 8);
    transpose_kernel<<<dim3(64, 64),  tb, 0, stream>>>(Wq, WqkvT,                       2048, 2048);
    transpose_kernel<<<dim3(64, 64),  tb, 0, stream>>>(Wk, WqkvT + (size_t)2048 * 2048, 2048, 2048);
    transpose_kernel<<<dim3(128, 64), tb, 0, stream>>>(Wv, WqkvT + (size_t)4096 * 2048, 2048, 4096);
    transpose_kernel<<<dim3(128, 64), tb, 0, stream>>>(Wg, WgT,                         2048, 4096);
    transpose_kernel<<<dim3(64, 128), tb, 0, stream>>>(Wo, WoT,                         4096, 2048);
    build_wab_kernel<<<dim3(8, 128), 256, 0, stream>>>(Wa, Wb, WabT);
    f2b_kernel<<<16384, 256, 0, stream>>>(h, hb, 2048 * 2048);

    gemm_bt_kernel<bf16> <<<dim3(16, 64), 256, 0, stream>>>(hb, WqkvT, mixed, 2048, 8192, 2048);
    gemm_bt_kernel<float><<<dim3(16, 1),  256, 0, stream>>>(hb, WabT,  ab,    2048, 128,  2048);
    gemm_bt_kernel<bf16> <<<dim3(16, 32), 256, 0, stream>>>(hb, WgT,   gate,  2048, 4096, 2048);

    conv_qk_kernel<<<dim3(2048, 32), 128, 0, stream>>>(mixed, conv_q, conv_k, qrt, krt);
    conv_v_kernel<<<32768, 256, 0, stream>>>(mixed, conv_v, vvb);
    transpose_bf_kernel<<<dim3(128, 64), tb, 0, stream>>>(vvb, vrt, 2048, 4096);
    gating_kernel<<<256, 256, 0, stream>>>(ab, dt_bias, A_log, ebz);

    recur_kernel<<<dim3(32, 8), 256, 0, stream>>>(qrt, krt, vrt, ebz, ob);
    normgate_kernel<<<16384, 256, 0, stream>>>(ob, gate, onw, og);

    gemm_bt_kernel<float><<<dim3(16, 16), 256, 0, stream>>>(og, WoT, out, 2048, 2048, 4096);
}